// Round 10
// baseline (214.724 us; speedup 1.0000x reference)
//
#include <hip/hip_runtime.h>
#include <hip/hip_bf16.h>
#include <math.h>

#define B 32
#define T 1024
#define AC 20
#define SE 16
#define H 64
#define NH 4
#define HD 16
#define NROW (B*T)      // 32768
#define BH (B*NH)       // 128
#define NCHUNK (T/32)   // 32 chunks of 32 keys
#define NSLOT 128       // stats accumulator slots (contention spread)

typedef unsigned short u16;
typedef short short8 __attribute__((ext_vector_type(8)));
typedef float f32x16 __attribute__((ext_vector_type(16)));
typedef unsigned int uintx4 __attribute__((ext_vector_type(4)));

// ---- workspace layout (float offsets) ----
#define F_KB   (BH*T*16/2)                   // bf16 K, 1M floats
#define F_VT   (BH*32768/2)                  // bf16 V2 32-row tiles, 2M floats
#define OFF_KB   0
#define OFF_VT   (OFF_KB + F_KB)             // V2 [bh][g=t/16][row 0..31][t%16]; row16=ones
#define OFF_ET   (OFF_VT + F_VT)             // f32 enhT [20ch][NROW]
#define OFF_WF   (OFF_ET + AC*NROW)
#define OFF_ACC  (OFF_WF + 5120)             // f32 accum[NSLOT][80]
#define OFF_ST   (OFF_ACC + NSLOT*80)        // f32 stats[40]
#define OFF_CNT  (OFF_ST + 40)               // u32 block-done counter

// fused-weight sub-offsets inside wf
#define WF_WQ 0
#define WF_BQ 1024
#define WF_WK 1088
#define WF_BK 2368
#define WF_WV 2432
#define WF_BV 3712
#define WF_WO 3776
#define WF_BO 5056
#define WF_TOTAL 5076

// 0.25 (1/sqrt(HD)) x log2(e): scores come out of MFMA in log2 domain
#define QSCALE 0.36067375670234045f

__device__ __forceinline__ u16 bf16b(float a) {
    __hip_bfloat16 t = __float2bfloat16(a);
    u16 u; __builtin_memcpy(&u, &t, 2); return u;
}
__device__ __forceinline__ unsigned packbf(float a, float b) {
    return (unsigned)bf16b(a) | ((unsigned)bf16b(b) << 16);
}

// ---------------- K0: fuse weights (+ zero stats accumulator slots + counter) ----------------
__global__ __launch_bounds__(256) void k_fuse(
    const float* __restrict__ Wq, const float* __restrict__ bq,
    const float* __restrict__ Wkv, const float* __restrict__ bkv,
    const float* __restrict__ in_w, const float* __restrict__ in_b,
    const float* __restrict__ out_w, const float* __restrict__ out_b,
    const float* __restrict__ proj_w, const float* __restrict__ proj_b,
    float* __restrict__ wf, float* __restrict__ accum,
    unsigned* __restrict__ cnt) {
    int idx = blockIdx.x * 256 + threadIdx.x;
    if (idx == 0) *cnt = 0u;                 // reset last-block counter every launch
    if (idx < NSLOT*40) {                    // zero accum[NSLOT][80], 2 per thread
        accum[idx] = 0.f;
        accum[idx + NSLOT*40] = 0.f;
    }
    if (idx >= WF_TOTAL) return;
    if (idx < WF_BQ) {                       // WqF[i][j] (scale 0.25*log2e folded)
        int i = idx >> 4, j = idx & 15;
        float s = 0.f;
        for (int m = 0; m < H; ++m) s += in_w[i*H + m] * Wq[m*SE + j];
        wf[idx] = QSCALE * s;
    } else if (idx < WF_WK) {                // bqF
        int i = idx - WF_BQ;
        float s = in_b[i];
        for (int m = 0; m < H; ++m) s += in_w[i*H + m] * bq[m];
        wf[idx] = QSCALE * s;
    } else if (idx < WF_BK) {                // WkF[i][j]
        int r = idx - WF_WK; int i = r / AC, j = r % AC;
        float s = 0.f;
        for (int m = 0; m < H; ++m) s += in_w[(H+i)*H + m] * Wkv[m*AC + j];
        wf[idx] = s;
    } else if (idx < WF_WV) {                // bkF
        int i = idx - WF_BK;
        float s = in_b[H + i];
        for (int m = 0; m < H; ++m) s += in_w[(H+i)*H + m] * bkv[m];
        wf[idx] = s;
    } else if (idx < WF_BV) {                // WvF[i][j]
        int r = idx - WF_WV; int i = r / AC, j = r % AC;
        float s = 0.f;
        for (int m = 0; m < H; ++m) s += in_w[(2*H+i)*H + m] * Wkv[(H+m)*AC + j];
        wf[idx] = s;
    } else if (idx < WF_WO) {                // bvF
        int i = idx - WF_BV;
        float s = in_b[2*H + i];
        for (int m = 0; m < H; ++m) s += in_w[(2*H+i)*H + m] * bkv[H + m];
        wf[idx] = s;
    } else if (idx < WF_BO) {                // WoF[c][d]
        int r = idx - WF_WO; int c = r >> 6, d = r & 63;
        float s = 0.f;
        for (int m = 0; m < H; ++m) s += proj_w[c*H + m] * out_w[m*H + d];
        wf[idx] = s;
    } else {                                 // boF
        int c = idx - WF_BO;
        float s = proj_b[c];
        for (int m = 0; m < H; ++m) s += proj_w[c*H + m] * out_b[m];
        wf[idx] = s;
    }
}

// ---------------- K1: fused KV projection ----------------
// block = 128 threads = 16 rows x 8 sections; sections 0-3 = K heads, 4-7 = V heads.
// V tile transposed through padded LDS -> coalesced dwordx4 global writes.
// V2 tile = 32 rows x 16 keys; rows 0-15 = V^T, row 16 = ones (MFMA denominator row).
__global__ __launch_bounds__(128) void k_qkv(
    const float* __restrict__ acst, const float* __restrict__ wf,
    u16* __restrict__ Kb, u16* __restrict__ Vtb) {
    __shared__ __align__(16) unsigned vls32[16*33];   // V tile [d][h*8+rp], stride-33 dwords
    const int tid = threadIdx.x;
    const int sec = tid >> 4, r = tid & 15;
    const int row = blockIdx.x * 16 + r;
    const int b = row >> 10, t = row & 1023;
    const int type = sec >> 2, h = sec & 3;           // type 0=K, 1=V
    float o[16];
    {
        float a[AC];
        const float4* ap = (const float4*)(acst + (size_t)row * AC);
        #pragma unroll
        for (int i = 0; i < 5; ++i) {
            float4 v = ap[i];
            a[4*i] = v.x; a[4*i+1] = v.y; a[4*i+2] = v.z; a[4*i+3] = v.w;
        }
        const float* wb = wf + (type == 0 ? WF_WK : WF_WV) + h*16*AC;
        const float* bb = wf + (type == 0 ? WF_BK : WF_BV) + h*16;
        #pragma unroll
        for (int ii = 0; ii < 16; ++ii) {
            float acc = bb[ii];
            #pragma unroll
            for (int j = 0; j < 5; ++j) {
                float4 w4 = *(const float4*)(wb + ii*AC + 4*j);
                acc += a[4*j]*w4.x + a[4*j+1]*w4.y + a[4*j+2]*w4.z + a[4*j+3]*w4.w;
            }
            o[ii] = acc;
        }
    }
    if (type == 0) {
        unsigned* dst = (unsigned*)(Kb + (((size_t)(b*NH + h))*T + t)*16);
        #pragma unroll
        for (int i = 0; i < 8; ++i) dst[i] = packbf(o[2*i], o[2*i+1]);
    } else {
        u16* v16 = (u16*)vls32;               // u16 idx = d*66 + h*16 + r (2-way banks = free)
        #pragma unroll
        for (int d = 0; d < HD; ++d) v16[d*66 + h*16 + r] = bf16b(o[d]);
    }
    __syncthreads();
    if (type == 1) {
        // copy V tile to global: thread (h2,li) owns dst row d=li of head h2
        const int l = tid - 64, h2 = l >> 4, li = l & 15;
        const int bb_ = blockIdx.x >> 6, g = blockIdx.x & 63;
        const size_t tile = (size_t)((bb_*NH + h2)*64 + g);
        unsigned tmp[8];
        #pragma unroll
        for (int k = 0; k < 8; ++k) tmp[k] = vls32[li*33 + h2*8 + k];
        unsigned* dst = (unsigned*)(Vtb + tile*512) + li*8;
        *(uintx4*)dst       = (uintx4){tmp[0], tmp[1], tmp[2], tmp[3]};
        *(uintx4*)(dst + 4) = (uintx4){tmp[4], tmp[5], tmp[6], tmp[7]};
        if (li == 0) {                        // denominator row 16 = bf16 ones
            unsigned* od = (unsigned*)(Vtb + tile*512 + 256);
            const unsigned one2 = 0x3F803F80u;
            *(uintx4*)od       = (uintx4){one2, one2, one2, one2};
            *(uintx4*)(od + 4) = (uintx4){one2, one2, one2, one2};
        }
    }
}

// ---------------- K2: Q-proj + MFMA flash attention + proj + residual + stats (+last-block reduce) ----------------
// block = 4 waves = 4 heads x 32 q-rows x full 1024 keys; grid = 1024
// b = blk&31: all 32 q-tiles of batch b land on XCD b%8 (K/V of 4 heads L2-local).
// Scores emerge in log2 domain (QSCALE folds log2e) -> exp2f, no per-element mul.
#define CSTR 66
__global__ __launch_bounds__(256, 4) void k_attn(
    const float* __restrict__ sem,
    const u16* __restrict__ Kb, const u16* __restrict__ Vtb,
    const float* __restrict__ acst, const float* __restrict__ wf,
    const float* __restrict__ rlogit,
    float* __restrict__ enhT, float* __restrict__ accum,
    float* __restrict__ stats, unsigned* __restrict__ cnt) {
    __shared__ __align__(16) float ctxs[32*CSTR];   // 8.25 KB, stride-66 (2-way banks = free)
    __shared__ __align__(16) float wsm[AC*H + AC];  // 5.2 KB out-proj weights
    __shared__ __align__(16) float wqs[16*H + H];   // 4.25 KB WqF + bqF
    __shared__ unsigned lastf;
    const int tid  = threadIdx.x;
    const int lane = tid & 63;
    const int wv   = tid >> 6;                      // wave = head
    for (int i = tid; i < AC*H + AC; i += 256) wsm[i] = wf[WF_WO + i];
    for (int i = tid; i < 16*H + H; i += 256) wqs[i] = wf[WF_WQ + i];
    const int blk  = blockIdx.x;
    const int b    = blk & 31;
    const int qblk = blk >> 5;
    const int l31 = lane & 31, hi2 = lane >> 5;
    const int bh = b*NH + wv;
    const int q0 = qblk*32;
    __syncthreads();

    // ---- Q fragment computed in-place (QSCALE folded in wqs) ----
    short8 qf;
    {
        float s[SE];
        const float4* sp = (const float4*)(sem + ((size_t)b*T + q0 + l31) * SE);
        #pragma unroll
        for (int i = 0; i < 4; ++i) {
            float4 v = sp[i];
            s[4*i] = v.x; s[4*i+1] = v.y; s[4*i+2] = v.z; s[4*i+3] = v.w;
        }
        #pragma unroll
        for (int jj = 0; jj < 8; ++jj) {
            const int ii = wv*16 + hi2*8 + jj;
            float acc0 = wqs[1024 + ii];
            #pragma unroll
            for (int j = 0; j < 4; ++j) {
                float4 w4 = *(const float4*)(wqs + ii*SE + 4*j);
                acc0 += s[4*j]*w4.x + s[4*j+1]*w4.y + s[4*j+2]*w4.z + s[4*j+3]*w4.w;
            }
            qf[jj] = (short)bf16b(acc0);
        }
    }

    // A-fragment K: K[key][d], key = lane&31 (+32/chunk), d = 8*hi2 + j
    const u16* kp = Kb + ((size_t)bh*T + l31)*16 + 8*hi2;
    // A-fragment V2: row = lane&31 (0-15 = d, 16 = ones), k-half by hi2; 1024 u16/chunk
    const u16* vp = Vtb + (size_t)bh*32768 + l31*16 + 8*hi2;

    f32x16 acc = {0.f,0.f,0.f,0.f,0.f,0.f,0.f,0.f,0.f,0.f,0.f,0.f,0.f,0.f,0.f,0.f};
    const f32x16 z16 = {0.f,0.f,0.f,0.f,0.f,0.f,0.f,0.f,0.f,0.f,0.f,0.f,0.f,0.f,0.f,0.f};

    auto chunk = [&](short8 kf, short8 va, short8 vb) {
        // scores^T[key][q] in log2 domain: C col = q (lane-local)
        f32x16 sc = __builtin_amdgcn_mfma_f32_32x32x16_bf16(kf, qf, z16, 0, 0, 0);
        float p[16];
        #pragma unroll
        for (int r = 0; r < 16; ++r) p[r] = exp2f(sc[r]);
        // pack P pairs with HW cvt (RNE)
        unsigned u0, u1, u2, u3, u4, u5, u6, u7;
        asm("v_cvt_pk_bf16_f32 %0, %1, %2" : "=v"(u0) : "v"(p[0]),  "v"(p[1]));
        asm("v_cvt_pk_bf16_f32 %0, %1, %2" : "=v"(u1) : "v"(p[2]),  "v"(p[3]));
        asm("v_cvt_pk_bf16_f32 %0, %1, %2" : "=v"(u2) : "v"(p[4]),  "v"(p[5]));
        asm("v_cvt_pk_bf16_f32 %0, %1, %2" : "=v"(u3) : "v"(p[6]),  "v"(p[7]));
        asm("v_cvt_pk_bf16_f32 %0, %1, %2" : "=v"(u4) : "v"(p[8]),  "v"(p[9]));
        asm("v_cvt_pk_bf16_f32 %0, %1, %2" : "=v"(u5) : "v"(p[10]), "v"(p[11]));
        asm("v_cvt_pk_bf16_f32 %0, %1, %2" : "=v"(u6) : "v"(p[12]), "v"(p[13]));
        asm("v_cvt_pk_bf16_f32 %0, %1, %2" : "=v"(u7) : "v"(p[14]), "v"(p[15]));
        // in-register transpose across lane halves (T12)
        asm("v_permlane32_swap_b32 %0, %1" : "+v"(u2), "+v"(u0));
        asm("v_permlane32_swap_b32 %0, %1" : "+v"(u3), "+v"(u1));
        asm("v_permlane32_swap_b32 %0, %1" : "+v"(u6), "+v"(u4));
        asm("v_permlane32_swap_b32 %0, %1" : "+v"(u7), "+v"(u5));
        uintx4 t1 = {u0, u1, u2, u3};
        uintx4 t2 = {u4, u5, u6, u7};
        short8 pf1 = __builtin_bit_cast(short8, t1);
        short8 pf2 = __builtin_bit_cast(short8, t2);
        acc = __builtin_amdgcn_mfma_f32_32x32x16_bf16(va, pf1, acc, 0, 0, 0);
        acc = __builtin_amdgcn_mfma_f32_32x32x16_bf16(vb, pf2, acc, 0, 0, 0);
    };

    // depth-2 software pipeline (static register rotation)
    short8 kfA = *(const short8*)kp;
    short8 vaA = *(const short8*)vp;
    short8 vbA = *(const short8*)(vp + 512);
    short8 kfB = *(const short8*)(kp + 512);
    short8 vaB = *(const short8*)(vp + 1024);
    short8 vbB = *(const short8*)(vp + 1536);
    for (int ch = 0; ch < NCHUNK; ch += 2) {
        const int n0 = (ch + 2 < NCHUNK) ? ch + 2 : ch;
        short8 kfN0 = *(const short8*)(kp + (size_t)n0*512);
        short8 vaN0 = *(const short8*)(vp + (size_t)n0*1024);
        short8 vbN0 = *(const short8*)(vp + (size_t)n0*1024 + 512);
        chunk(kfA, vaA, vbA);
        const int n1 = (ch + 3 < NCHUNK) ? ch + 3 : ch + 1;
        short8 kfN1 = *(const short8*)(kp + (size_t)n1*512);
        short8 vaN1 = *(const short8*)(vp + (size_t)n1*1024);
        short8 vbN1 = *(const short8*)(vp + (size_t)n1*1024 + 512);
        chunk(kfB, vaB, vbB);
        kfA = kfN0; vaA = vaN0; vbA = vbN0;
        kfB = kfN1; vaB = vaN1; vbB = vbN1;
    }

    // denominator: C-row 16 = ones-row dot P = sum over all keys of bf16(P)
    const float ls = __shfl(acc[8], l31);   // lane l31 has hi2=0 -> row 16
    const float inv = 1.f / ls;
    #pragma unroll
    for (int r = 0; r < 8; ++r) {           // regs 0-7 = d rows 0-15
        const int d = (r & 3) + 8*(r >> 2) + 4*hi2;
        ctxs[l31*CSTR + wv*16 + d] = acc[r] * inv;
    }
    __syncthreads();

    // ---- fused output proj + residual + slot-spread channel stats ----
    const int rq = tid & 31, g = tid >> 5;  // half-wave g owns channels {g+8j}
    const int row = b*T + q0 + rq;
    const float sg = 1.f / (1.f + __expf(-rlogit[0]));
    float* slot = accum + (size_t)(blk & (NSLOT-1)) * 80;
    const int nj = (g < 4) ? 3 : 2;         // wave-uniform (g paired per wave)
    for (int j = 0; j < nj; ++j) {
        const int ch = g + 8*j;
        float s = wsm[AC*H + ch];
        #pragma unroll
        for (int kc = 0; kc < 4; ++kc) {    // k-chunked dot, scalar LDS reads
            float c0 = ctxs[rq*CSTR + kc*16 +  0], c1 = ctxs[rq*CSTR + kc*16 +  1];
            float c2 = ctxs[rq*CSTR + kc*16 +  2], c3 = ctxs[rq*CSTR + kc*16 +  3];
            float c4 = ctxs[rq*CSTR + kc*16 +  4], c5 = ctxs[rq*CSTR + kc*16 +  5];
            float c6 = ctxs[rq*CSTR + kc*16 +  6], c7 = ctxs[rq*CSTR + kc*16 +  7];
            float c8 = ctxs[rq*CSTR + kc*16 +  8], c9 = ctxs[rq*CSTR + kc*16 +  9];
            float cA = ctxs[rq*CSTR + kc*16 + 10], cB = ctxs[rq*CSTR + kc*16 + 11];
            float cC = ctxs[rq*CSTR + kc*16 + 12], cD = ctxs[rq*CSTR + kc*16 + 13];
            float cE = ctxs[rq*CSTR + kc*16 + 14], cF = ctxs[rq*CSTR + kc*16 + 15];
            const float* w = wsm + ch*H + kc*16;
            s += c0*w[0] + c1*w[1] + c2*w[2] + c3*w[3]
               + c4*w[4] + c5*w[5] + c6*w[6] + c7*w[7]
               + c8*w[8] + c9*w[9] + cA*w[10] + cB*w[11]
               + cC*w[12] + cD*w[13] + cE*w[14] + cF*w[15];
        }
        const float a = acst[(size_t)row*AC + ch];
        const float e = a + sg * s;
        enhT[(size_t)ch * NROW + row] = e;
        float sa = a, qa = a*a, se = e, qe = e*e;
        #pragma unroll
        for (int m = 1; m <= 16; m <<= 1) { // reduce within 32-lane half-wave
            sa += __shfl_xor(sa, m); qa += __shfl_xor(qa, m);
            se += __shfl_xor(se, m); qe += __shfl_xor(qe, m);
        }
        if (rq == 0) {
            atomicAdd(&slot[ch*4+0], sa);
            atomicAdd(&slot[ch*4+1], qa);
            atomicAdd(&slot[ch*4+2], se);
            atomicAdd(&slot[ch*4+3], qe);
        }
    }

    // ---- last-block-done: slot reduction + (mu,corr), replaces k_stats2 dispatch ----
    __threadfence();                        // release our slot atomics
    __syncthreads();
    if (tid == 0) lastf = (atomicAdd(cnt, 1u) == 1023u) ? 1u : 0u;
    __syncthreads();
    if (lastf) {
        __threadfence();                    // acquire all blocks' atomics
        float* red = ctxs;                  // reuse LDS (all prior reads barriered)
        if (tid < 80) {
            float s0 = 0.f, s1 = 0.f, s2 = 0.f, s3 = 0.f;
            #pragma unroll 8
            for (int sl = 0; sl < NSLOT; sl += 4) {
                s0 += accum[(size_t)sl*80 + tid];
                s1 += accum[(size_t)(sl+1)*80 + tid];
                s2 += accum[(size_t)(sl+2)*80 + tid];
                s3 += accum[(size_t)(sl+3)*80 + tid];
            }
            red[tid] = (s0 + s1) + (s2 + s3);
        }
        __syncthreads();
        if (tid < AC) {
            const float Nf = (float)NROW;
            float sa = red[tid*4+0], qa = red[tid*4+1];
            float se = red[tid*4+2], qe = red[tid*4+3];
            float mu  = sa / Nf;
            float va  = (qa - sa*sa/Nf) / (Nf - 1.f);
            float sda = sqrtf(fmaxf(va, 0.f));
            float osd = sda + 1e-8f;
            float ve  = (qe - se*se/Nf) / (Nf - 1.f);
            float sde = sqrtf(fmaxf(ve, 0.f));
            float ratio = (sde / osd) / (sda / osd + 1e-8f);
            float corr  = (ratio < 0.4f) ? (0.4f / ratio) : 1.f;
            stats[tid*2]   = mu;
            stats[tid*2+1] = corr;
        }
    }
}

// ---------------- K3: std-correction + LayerNorm (reads precomputed stats) ----------------
__global__ __launch_bounds__(128) void k_final(
    const float* __restrict__ enhT, const float* __restrict__ stats,
    const float* __restrict__ gamma, const float* __restrict__ beta,
    float* __restrict__ out) {
    __shared__ float acs[40];
    const int tx = threadIdx.x;
    if (tx < 40) acs[tx] = stats[tx];
    __syncthreads();
    int row = blockIdx.x * 128 + tx;
    float ef[AC];
    #pragma unroll
    for (int c = 0; c < AC; ++c) {
        float mu = acs[c*2], corr = acs[c*2+1];
        float e = enhT[(size_t)c * NROW + row];
        ef[c] = (e - mu) * corr + mu;
    }
    float m = 0.f;
    #pragma unroll
    for (int c = 0; c < AC; ++c) m += ef[c];
    m *= (1.f / AC);
    float v = 0.f;
    #pragma unroll
    for (int c = 0; c < AC; ++c) { float d = ef[c] - m; v += d*d; }
    v *= (1.f / AC);
    float inv = rsqrtf(v + 1e-5f);
    float o[AC];
    #pragma unroll
    for (int c = 0; c < AC; ++c) o[c] = (ef[c] - m) * inv * gamma[c] + beta[c];
    float4* op = (float4*)(out + (size_t)row * AC);
    #pragma unroll
    for (int i = 0; i < 5; ++i)
        op[i] = make_float4(o[4*i], o[4*i+1], o[4*i+2], o[4*i+3]);
}

extern "C" void kernel_launch(void* const* d_in, const int* in_sizes, int n_in,
                              void* d_out, int out_size, void* d_ws, size_t ws_size,
                              hipStream_t stream) {
    (void)in_sizes; (void)n_in; (void)out_size; (void)ws_size;
    const float* acoustic = (const float*)d_in[0];
    const float* semantic = (const float*)d_in[1];
    const float* Wq     = (const float*)d_in[2];
    const float* bq     = (const float*)d_in[3];
    const float* Wkv    = (const float*)d_in[4];
    const float* bkv    = (const float*)d_in[5];
    const float* in_w   = (const float*)d_in[6];
    const float* in_b   = (const float*)d_in[7];
    const float* out_w  = (const float*)d_in[8];
    const float* out_b  = (const float*)d_in[9];
    const float* proj_w = (const float*)d_in[10];
    const float* proj_b = (const float*)d_in[11];
    const float* rlogit = (const float*)d_in[12];
    const float* gamma  = (const float*)d_in[13];
    const float* beta   = (const float*)d_in[14];
    float* ws = (float*)d_ws;
    u16* Kb  = (u16*)(ws + OFF_KB);
    u16* Vtb = (u16*)(ws + OFF_VT);
    float* enhT  = ws + OFF_ET;
    float* wf    = ws + OFF_WF;
    float* accum = ws + OFF_ACC;
    float* stats = ws + OFF_ST;
    unsigned* cnt = (unsigned*)(ws + OFF_CNT);
    float* out = (float*)d_out;

    k_fuse<<<(WF_TOTAL + 255)/256, 256, 0, stream>>>(Wq, bq, Wkv, bkv, in_w, in_b,
                                                     out_w, out_b, proj_w, proj_b, wf, accum, cnt);
    k_qkv<<<NROW/16, 128, 0, stream>>>(acoustic, wf, Kb, Vtb);
    k_attn<<<1024, 256, 0, stream>>>(semantic, Kb, Vtb, acoustic, wf, rlogit,
                                     enhT, accum, stats, cnt);
    k_final<<<NROW/128, 128, 0, stream>>>(enhT, stats, gamma, beta, out);
}

// Round 11
// 154.035 us; speedup vs baseline: 1.3940x; 1.3940x over previous
//
#include <hip/hip_runtime.h>
#include <hip/hip_bf16.h>
#include <math.h>

#define B 32
#define T 1024
#define AC 20
#define SE 16
#define H 64
#define NH 4
#define HD 16
#define NROW (B*T)      // 32768
#define BH (B*NH)       // 128
#define NCHUNK (T/32)   // 32 chunks of 32 keys
#define NSLOT 128       // stats accumulator slots (contention spread)

typedef unsigned short u16;
typedef short short8 __attribute__((ext_vector_type(8)));
typedef float f32x16 __attribute__((ext_vector_type(16)));
typedef unsigned int uintx4 __attribute__((ext_vector_type(4)));

// ---- workspace layout (float offsets) ----
#define F_KB   (BH*T*16/2)                   // bf16 K, 1M floats
#define F_VT   (BH*32768/2)                  // bf16 V2 32-row tiles, 2M floats
#define OFF_KB   0
#define OFF_VT   (OFF_KB + F_KB)             // V2 [bh][g=t/16][row 0..31][t%16]; row16=ones
#define OFF_ET   (OFF_VT + F_VT)             // f32 enhT [20ch][NROW]
#define OFF_WF   (OFF_ET + AC*NROW)
#define OFF_ACC  (OFF_WF + 5120)             // f32 accum[NSLOT][80]
#define OFF_ST   (OFF_ACC + NSLOT*80)        // f32 stats[40]

// fused-weight sub-offsets inside wf
#define WF_WQ 0
#define WF_BQ 1024
#define WF_WK 1088
#define WF_BK 2368
#define WF_WV 2432
#define WF_BV 3712
#define WF_WO 3776
#define WF_BO 5056
#define WF_TOTAL 5076

// 0.25 (1/sqrt(HD)) x log2(e): scores come out of MFMA in log2 domain
#define QSCALE 0.36067375670234045f

__device__ __forceinline__ u16 bf16b(float a) {
    __hip_bfloat16 t = __float2bfloat16(a);
    u16 u; __builtin_memcpy(&u, &t, 2); return u;
}
__device__ __forceinline__ unsigned packbf(float a, float b) {
    return (unsigned)bf16b(a) | ((unsigned)bf16b(b) << 16);
}

// ---------------- K0: fuse weights (+ zero stats accumulator slots) ----------------
__global__ __launch_bounds__(256) void k_fuse(
    const float* __restrict__ Wq, const float* __restrict__ bq,
    const float* __restrict__ Wkv, const float* __restrict__ bkv,
    const float* __restrict__ in_w, const float* __restrict__ in_b,
    const float* __restrict__ out_w, const float* __restrict__ out_b,
    const float* __restrict__ proj_w, const float* __restrict__ proj_b,
    float* __restrict__ wf, float* __restrict__ accum) {
    int idx = blockIdx.x * 256 + threadIdx.x;
    if (idx < NSLOT*40) {                    // zero accum[NSLOT][80], 2 per thread
        accum[idx] = 0.f;
        accum[idx + NSLOT*40] = 0.f;
    }
    if (idx >= WF_TOTAL) return;
    if (idx < WF_BQ) {                       // WqF[i][j] (scale 0.25*log2e folded)
        int i = idx >> 4, j = idx & 15;
        float s = 0.f;
        for (int m = 0; m < H; ++m) s += in_w[i*H + m] * Wq[m*SE + j];
        wf[idx] = QSCALE * s;
    } else if (idx < WF_WK) {                // bqF
        int i = idx - WF_BQ;
        float s = in_b[i];
        for (int m = 0; m < H; ++m) s += in_w[i*H + m] * bq[m];
        wf[idx] = QSCALE * s;
    } else if (idx < WF_BK) {                // WkF[i][j]
        int r = idx - WF_WK; int i = r / AC, j = r % AC;
        float s = 0.f;
        for (int m = 0; m < H; ++m) s += in_w[(H+i)*H + m] * Wkv[m*AC + j];
        wf[idx] = s;
    } else if (idx < WF_WV) {                // bkF
        int i = idx - WF_BK;
        float s = in_b[H + i];
        for (int m = 0; m < H; ++m) s += in_w[(H+i)*H + m] * bkv[m];
        wf[idx] = s;
    } else if (idx < WF_BV) {                // WvF[i][j]
        int r = idx - WF_WV; int i = r / AC, j = r % AC;
        float s = 0.f;
        for (int m = 0; m < H; ++m) s += in_w[(2*H+i)*H + m] * Wkv[(H+m)*AC + j];
        wf[idx] = s;
    } else if (idx < WF_WO) {                // bvF
        int i = idx - WF_BV;
        float s = in_b[2*H + i];
        for (int m = 0; m < H; ++m) s += in_w[(2*H+i)*H + m] * bkv[H + m];
        wf[idx] = s;
    } else if (idx < WF_BO) {                // WoF[c][d]
        int r = idx - WF_WO; int c = r >> 6, d = r & 63;
        float s = 0.f;
        for (int m = 0; m < H; ++m) s += proj_w[c*H + m] * out_w[m*H + d];
        wf[idx] = s;
    } else {                                 // boF
        int c = idx - WF_BO;
        float s = proj_b[c];
        for (int m = 0; m < H; ++m) s += proj_w[c*H + m] * out_b[m];
        wf[idx] = s;
    }
}

// ---------------- K1: fused KV projection ----------------
// block = 128 threads = 16 rows x 8 sections; sections 0-3 = K heads, 4-7 = V heads.
// V tile transposed through padded LDS -> coalesced dwordx4 global writes.
// V2 tile = 32 rows x 16 keys; rows 0-15 = V^T, row 16 = ones (MFMA denominator row).
__global__ __launch_bounds__(128) void k_qkv(
    const float* __restrict__ acst, const float* __restrict__ wf,
    u16* __restrict__ Kb, u16* __restrict__ Vtb) {
    __shared__ __align__(16) unsigned vls32[16*33];   // V tile [d][h*8+rp], stride-33 dwords
    const int tid = threadIdx.x;
    const int sec = tid >> 4, r = tid & 15;
    const int row = blockIdx.x * 16 + r;
    const int b = row >> 10, t = row & 1023;
    const int type = sec >> 2, h = sec & 3;           // type 0=K, 1=V
    float o[16];
    {
        float a[AC];
        const float4* ap = (const float4*)(acst + (size_t)row * AC);
        #pragma unroll
        for (int i = 0; i < 5; ++i) {
            float4 v = ap[i];
            a[4*i] = v.x; a[4*i+1] = v.y; a[4*i+2] = v.z; a[4*i+3] = v.w;
        }
        const float* wb = wf + (type == 0 ? WF_WK : WF_WV) + h*16*AC;
        const float* bb = wf + (type == 0 ? WF_BK : WF_BV) + h*16;
        #pragma unroll
        for (int ii = 0; ii < 16; ++ii) {
            float acc = bb[ii];
            #pragma unroll
            for (int j = 0; j < 5; ++j) {
                float4 w4 = *(const float4*)(wb + ii*AC + 4*j);
                acc += a[4*j]*w4.x + a[4*j+1]*w4.y + a[4*j+2]*w4.z + a[4*j+3]*w4.w;
            }
            o[ii] = acc;
        }
    }
    if (type == 0) {
        unsigned* dst = (unsigned*)(Kb + (((size_t)(b*NH + h))*T + t)*16);
        #pragma unroll
        for (int i = 0; i < 8; ++i) dst[i] = packbf(o[2*i], o[2*i+1]);
    } else {
        u16* v16 = (u16*)vls32;               // u16 idx = d*66 + h*16 + r (2-way banks = free)
        #pragma unroll
        for (int d = 0; d < HD; ++d) v16[d*66 + h*16 + r] = bf16b(o[d]);
    }
    __syncthreads();
    if (type == 1) {
        // copy V tile to global: thread (h2,li) owns dst row d=li of head h2
        const int l = tid - 64, h2 = l >> 4, li = l & 15;
        const int bb_ = blockIdx.x >> 6, g = blockIdx.x & 63;
        const size_t tile = (size_t)((bb_*NH + h2)*64 + g);
        unsigned tmp[8];
        #pragma unroll
        for (int k = 0; k < 8; ++k) tmp[k] = vls32[li*33 + h2*8 + k];
        unsigned* dst = (unsigned*)(Vtb + tile*512) + li*8;
        *(uintx4*)dst       = (uintx4){tmp[0], tmp[1], tmp[2], tmp[3]};
        *(uintx4*)(dst + 4) = (uintx4){tmp[4], tmp[5], tmp[6], tmp[7]};
        if (li == 0) {                        // denominator row 16 = bf16 ones
            unsigned* od = (unsigned*)(Vtb + tile*512 + 256);
            const unsigned one2 = 0x3F803F80u;
            *(uintx4*)od       = (uintx4){one2, one2, one2, one2};
            *(uintx4*)(od + 4) = (uintx4){one2, one2, one2, one2};
        }
    }
}

// ---------------- K2: Q-proj + MFMA flash attention + output proj + residual + stats ----------------
// block = 4 waves = 4 heads x 32 q-rows x full 1024 keys; grid = 1024
// b = blk&31: all 32 q-tiles of batch b land on XCD b%8 (K/V of 4 heads L2-local).
// Scores emerge in log2 domain (QSCALE folds log2e) -> exp2f, no per-element mul.
// NOTE (R10 lesson): NO per-block __threadfence here — device-scope fence on gfx950
// = L2 writeback storm (120 us k_attn). Stats reduction stays a separate dispatch.
#define CSTR 66
__global__ __launch_bounds__(256, 4) void k_attn(
    const float* __restrict__ sem,
    const u16* __restrict__ Kb, const u16* __restrict__ Vtb,
    const float* __restrict__ acst, const float* __restrict__ wf,
    const float* __restrict__ rlogit,
    float* __restrict__ enhT, float* __restrict__ accum) {
    __shared__ __align__(16) float ctxs[32*CSTR];   // 8.25 KB, stride-66 (2-way banks = free)
    __shared__ __align__(16) float wsm[AC*H + AC];  // 5.2 KB out-proj weights
    __shared__ __align__(16) float wqs[16*H + H];   // 4.25 KB WqF + bqF
    const int tid  = threadIdx.x;
    const int lane = tid & 63;
    const int wv   = tid >> 6;                      // wave = head
    for (int i = tid; i < AC*H + AC; i += 256) wsm[i] = wf[WF_WO + i];
    for (int i = tid; i < 16*H + H; i += 256) wqs[i] = wf[WF_WQ + i];
    const int blk  = blockIdx.x;
    const int b    = blk & 31;
    const int qblk = blk >> 5;
    const int l31 = lane & 31, hi2 = lane >> 5;
    const int bh = b*NH + wv;
    const int q0 = qblk*32;
    __syncthreads();

    // ---- Q fragment computed in-place (QSCALE folded in wqs) ----
    short8 qf;
    {
        float s[SE];
        const float4* sp = (const float4*)(sem + ((size_t)b*T + q0 + l31) * SE);
        #pragma unroll
        for (int i = 0; i < 4; ++i) {
            float4 v = sp[i];
            s[4*i] = v.x; s[4*i+1] = v.y; s[4*i+2] = v.z; s[4*i+3] = v.w;
        }
        #pragma unroll
        for (int jj = 0; jj < 8; ++jj) {
            const int ii = wv*16 + hi2*8 + jj;
            float acc0 = wqs[1024 + ii];
            #pragma unroll
            for (int j = 0; j < 4; ++j) {
                float4 w4 = *(const float4*)(wqs + ii*SE + 4*j);
                acc0 += s[4*j]*w4.x + s[4*j+1]*w4.y + s[4*j+2]*w4.z + s[4*j+3]*w4.w;
            }
            qf[jj] = (short)bf16b(acc0);
        }
    }

    // A-fragment K: K[key][d], key = lane&31 (+32/chunk), d = 8*hi2 + j
    const u16* kp = Kb + ((size_t)bh*T + l31)*16 + 8*hi2;
    // A-fragment V2: row = lane&31 (0-15 = d, 16 = ones), k-half by hi2; 1024 u16/chunk
    const u16* vp = Vtb + (size_t)bh*32768 + l31*16 + 8*hi2;

    f32x16 acc = {0.f,0.f,0.f,0.f,0.f,0.f,0.f,0.f,0.f,0.f,0.f,0.f,0.f,0.f,0.f,0.f};
    const f32x16 z16 = {0.f,0.f,0.f,0.f,0.f,0.f,0.f,0.f,0.f,0.f,0.f,0.f,0.f,0.f,0.f,0.f};

    auto chunk = [&](short8 kf, short8 va, short8 vb) {
        // scores^T[key][q] in log2 domain: C col = q (lane-local)
        f32x16 sc = __builtin_amdgcn_mfma_f32_32x32x16_bf16(kf, qf, z16, 0, 0, 0);
        float p[16];
        #pragma unroll
        for (int r = 0; r < 16; ++r) p[r] = exp2f(sc[r]);
        // pack P pairs with HW cvt (RNE)
        unsigned u0, u1, u2, u3, u4, u5, u6, u7;
        asm("v_cvt_pk_bf16_f32 %0, %1, %2" : "=v"(u0) : "v"(p[0]),  "v"(p[1]));
        asm("v_cvt_pk_bf16_f32 %0, %1, %2" : "=v"(u1) : "v"(p[2]),  "v"(p[3]));
        asm("v_cvt_pk_bf16_f32 %0, %1, %2" : "=v"(u2) : "v"(p[4]),  "v"(p[5]));
        asm("v_cvt_pk_bf16_f32 %0, %1, %2" : "=v"(u3) : "v"(p[6]),  "v"(p[7]));
        asm("v_cvt_pk_bf16_f32 %0, %1, %2" : "=v"(u4) : "v"(p[8]),  "v"(p[9]));
        asm("v_cvt_pk_bf16_f32 %0, %1, %2" : "=v"(u5) : "v"(p[10]), "v"(p[11]));
        asm("v_cvt_pk_bf16_f32 %0, %1, %2" : "=v"(u6) : "v"(p[12]), "v"(p[13]));
        asm("v_cvt_pk_bf16_f32 %0, %1, %2" : "=v"(u7) : "v"(p[14]), "v"(p[15]));
        // in-register transpose across lane halves (T12)
        asm("v_permlane32_swap_b32 %0, %1" : "+v"(u2), "+v"(u0));
        asm("v_permlane32_swap_b32 %0, %1" : "+v"(u3), "+v"(u1));
        asm("v_permlane32_swap_b32 %0, %1" : "+v"(u6), "+v"(u4));
        asm("v_permlane32_swap_b32 %0, %1" : "+v"(u7), "+v"(u5));
        uintx4 t1 = {u0, u1, u2, u3};
        uintx4 t2 = {u4, u5, u6, u7};
        short8 pf1 = __builtin_bit_cast(short8, t1);
        short8 pf2 = __builtin_bit_cast(short8, t2);
        acc = __builtin_amdgcn_mfma_f32_32x32x16_bf16(va, pf1, acc, 0, 0, 0);
        acc = __builtin_amdgcn_mfma_f32_32x32x16_bf16(vb, pf2, acc, 0, 0, 0);
    };

    // depth-2 software pipeline (static register rotation)
    short8 kfA = *(const short8*)kp;
    short8 vaA = *(const short8*)vp;
    short8 vbA = *(const short8*)(vp + 512);
    short8 kfB = *(const short8*)(kp + 512);
    short8 vaB = *(const short8*)(vp + 1024);
    short8 vbB = *(const short8*)(vp + 1536);
    for (int ch = 0; ch < NCHUNK; ch += 2) {
        const int n0 = (ch + 2 < NCHUNK) ? ch + 2 : ch;
        short8 kfN0 = *(const short8*)(kp + (size_t)n0*512);
        short8 vaN0 = *(const short8*)(vp + (size_t)n0*1024);
        short8 vbN0 = *(const short8*)(vp + (size_t)n0*1024 + 512);
        chunk(kfA, vaA, vbA);
        const int n1 = (ch + 3 < NCHUNK) ? ch + 3 : ch + 1;
        short8 kfN1 = *(const short8*)(kp + (size_t)n1*512);
        short8 vaN1 = *(const short8*)(vp + (size_t)n1*1024);
        short8 vbN1 = *(const short8*)(vp + (size_t)n1*1024 + 512);
        chunk(kfB, vaB, vbB);
        kfA = kfN0; vaA = vaN0; vbA = vbN0;
        kfB = kfN1; vaB = vaN1; vbB = vbN1;
    }

    // denominator: C-row 16 = ones-row dot P = sum over all keys of bf16(P)
    const float ls = __shfl(acc[8], l31);   // lane l31 has hi2=0 -> row 16
    const float inv = 1.f / ls;
    #pragma unroll
    for (int r = 0; r < 8; ++r) {           // regs 0-7 = d rows 0-15
        const int d = (r & 3) + 8*(r >> 2) + 4*hi2;
        ctxs[l31*CSTR + wv*16 + d] = acc[r] * inv;
    }
    __syncthreads();

    // ---- fused output proj + residual + slot-spread channel stats ----
    const int rq = tid & 31, g = tid >> 5;  // half-wave g owns channels {g+8j}
    const int row = b*T + q0 + rq;
    const float sg = 1.f / (1.f + __expf(-rlogit[0]));
    float* slot = accum + (size_t)(blk & (NSLOT-1)) * 80;
    const int nj = (g < 4) ? 3 : 2;         // wave-uniform (g paired per wave)
    for (int j = 0; j < nj; ++j) {
        const int ch = g + 8*j;
        float s = wsm[AC*H + ch];
        #pragma unroll
        for (int kc = 0; kc < 4; ++kc) {    // k-chunked dot, scalar LDS reads
            float c0 = ctxs[rq*CSTR + kc*16 +  0], c1 = ctxs[rq*CSTR + kc*16 +  1];
            float c2 = ctxs[rq*CSTR + kc*16 +  2], c3 = ctxs[rq*CSTR + kc*16 +  3];
            float c4 = ctxs[rq*CSTR + kc*16 +  4], c5 = ctxs[rq*CSTR + kc*16 +  5];
            float c6 = ctxs[rq*CSTR + kc*16 +  6], c7 = ctxs[rq*CSTR + kc*16 +  7];
            float c8 = ctxs[rq*CSTR + kc*16 +  8], c9 = ctxs[rq*CSTR + kc*16 +  9];
            float cA = ctxs[rq*CSTR + kc*16 + 10], cB = ctxs[rq*CSTR + kc*16 + 11];
            float cC = ctxs[rq*CSTR + kc*16 + 12], cD = ctxs[rq*CSTR + kc*16 + 13];
            float cE = ctxs[rq*CSTR + kc*16 + 14], cF = ctxs[rq*CSTR + kc*16 + 15];
            const float* w = wsm + ch*H + kc*16;
            s += c0*w[0] + c1*w[1] + c2*w[2] + c3*w[3]
               + c4*w[4] + c5*w[5] + c6*w[6] + c7*w[7]
               + c8*w[8] + c9*w[9] + cA*w[10] + cB*w[11]
               + cC*w[12] + cD*w[13] + cE*w[14] + cF*w[15];
        }
        const float a = acst[(size_t)row*AC + ch];
        const float e = a + sg * s;
        enhT[(size_t)ch * NROW + row] = e;
        float sa = a, qa = a*a, se = e, qe = e*e;
        #pragma unroll
        for (int m = 1; m <= 16; m <<= 1) { // reduce within 32-lane half-wave
            sa += __shfl_xor(sa, m); qa += __shfl_xor(qa, m);
            se += __shfl_xor(se, m); qe += __shfl_xor(qe, m);
        }
        if (rq == 0) {
            atomicAdd(&slot[ch*4+0], sa);
            atomicAdd(&slot[ch*4+1], qa);
            atomicAdd(&slot[ch*4+2], se);
            atomicAdd(&slot[ch*4+3], qe);
        }
    }
}

// ---------------- K3: reduce accumulator slots -> per-channel (mu, corr) ----------------
// one block, 640 threads = 80 counters x 8 slot-parts (16 slots each)
__global__ __launch_bounds__(640) void k_stats2(
    const float* __restrict__ accum, float* __restrict__ stats) {
    __shared__ float red[80*8];
    __shared__ float acs[80];
    const int tx = threadIdx.x;
    const int c = tx >> 3, p = tx & 7;
    float s0 = 0.f, s1 = 0.f, s2 = 0.f, s3 = 0.f;
    #pragma unroll
    for (int i = 0; i < 4; ++i) {
        int sl = p + (4*i)*8;
        s0 += accum[(size_t)sl*80 + c];
        s1 += accum[(size_t)(sl+8)*80 + c];
        s2 += accum[(size_t)(sl+16)*80 + c];
        s3 += accum[(size_t)(sl+24)*80 + c];
    }
    red[c*8 + p] = (s0 + s1) + (s2 + s3);
    __syncthreads();
    if (tx < 80) {
        float t = 0.f;
        #pragma unroll
        for (int i = 0; i < 8; ++i) t += red[tx*8 + i];
        acs[tx] = t;
    }
    __syncthreads();
    if (tx < AC) {
        const float Nf = (float)NROW;
        float sa = acs[tx*4+0], qa = acs[tx*4+1];
        float se = acs[tx*4+2], qe = acs[tx*4+3];
        float mu  = sa / Nf;
        float va  = (qa - sa*sa/Nf) / (Nf - 1.f);
        float sda = sqrtf(fmaxf(va, 0.f));
        float osd = sda + 1e-8f;
        float ve  = (qe - se*se/Nf) / (Nf - 1.f);
        float sde = sqrtf(fmaxf(ve, 0.f));
        float ratio = (sde / osd) / (sda / osd + 1e-8f);
        float corr  = (ratio < 0.4f) ? (0.4f / ratio) : 1.f;
        stats[tx*2]   = mu;
        stats[tx*2+1] = corr;
    }
}

// ---------------- K4: std-correction + LayerNorm (reads precomputed stats) ----------------
__global__ __launch_bounds__(128) void k_final(
    const float* __restrict__ enhT, const float* __restrict__ stats,
    const float* __restrict__ gamma, const float* __restrict__ beta,
    float* __restrict__ out) {
    __shared__ float acs[40];
    const int tx = threadIdx.x;
    if (tx < 40) acs[tx] = stats[tx];
    __syncthreads();
    int row = blockIdx.x * 128 + tx;
    float ef[AC];
    #pragma unroll
    for (int c = 0; c < AC; ++c) {
        float mu = acs[c*2], corr = acs[c*2+1];
        float e = enhT[(size_t)c * NROW + row];
        ef[c] = (e - mu) * corr + mu;
    }
    float m = 0.f;
    #pragma unroll
    for (int c = 0; c < AC; ++c) m += ef[c];
    m *= (1.f / AC);
    float v = 0.f;
    #pragma unroll
    for (int c = 0; c < AC; ++c) { float d = ef[c] - m; v += d*d; }
    v *= (1.f / AC);
    float inv = rsqrtf(v + 1e-5f);
    float o[AC];
    #pragma unroll
    for (int c = 0; c < AC; ++c) o[c] = (ef[c] - m) * inv * gamma[c] + beta[c];
    float4* op = (float4*)(out + (size_t)row * AC);
    #pragma unroll
    for (int i = 0; i < 5; ++i)
        op[i] = make_float4(o[4*i], o[4*i+1], o[4*i+2], o[4*i+3]);
}

extern "C" void kernel_launch(void* const* d_in, const int* in_sizes, int n_in,
                              void* d_out, int out_size, void* d_ws, size_t ws_size,
                              hipStream_t stream) {
    (void)in_sizes; (void)n_in; (void)out_size; (void)ws_size;
    const float* acoustic = (const float*)d_in[0];
    const float* semantic = (const float*)d_in[1];
    const float* Wq     = (const float*)d_in[2];
    const float* bq     = (const float*)d_in[3];
    const float* Wkv    = (const float*)d_in[4];
    const float* bkv    = (const float*)d_in[5];
    const float* in_w   = (const float*)d_in[6];
    const float* in_b   = (const float*)d_in[7];
    const float* out_w  = (const float*)d_in[8];
    const float* out_b  = (const float*)d_in[9];
    const float* proj_w = (const float*)d_in[10];
    const float* proj_b = (const float*)d_in[11];
    const float* rlogit = (const float*)d_in[12];
    const float* gamma  = (const float*)d_in[13];
    const float* beta   = (const float*)d_in[14];
    float* ws = (float*)d_ws;
    u16* Kb  = (u16*)(ws + OFF_KB);
    u16* Vtb = (u16*)(ws + OFF_VT);
    float* enhT  = ws + OFF_ET;
    float* wf    = ws + OFF_WF;
    float* accum = ws + OFF_ACC;
    float* stats = ws + OFF_ST;
    float* out = (float*)d_out;

    k_fuse<<<(WF_TOTAL + 255)/256, 256, 0, stream>>>(Wq, bq, Wkv, bkv, in_w, in_b,
                                                     out_w, out_b, proj_w, proj_b, wf, accum);
    k_qkv<<<NROW/16, 128, 0, stream>>>(acoustic, wf, Kb, Vtb);
    k_attn<<<1024, 256, 0, stream>>>(semantic, Kb, Vtb, acoustic, wf, rlogit, enhT, accum);
    k_stats2<<<1, 640, 0, stream>>>(accum, stats);
    k_final<<<NROW/128, 128, 0, stream>>>(enhT, stats, gamma, beta, out);
}

// Round 12
// 138.153 us; speedup vs baseline: 1.5543x; 1.1150x over previous
//
#include <hip/hip_runtime.h>
#include <hip/hip_bf16.h>
#include <math.h>

#define B 32
#define T 1024
#define AC 20
#define SE 16
#define H 64
#define NH 4
#define HD 16
#define NROW (B*T)      // 32768
#define BH (B*NH)       // 128
#define NCHUNK (T/32)   // 32 chunks of 32 keys
#define NSLOT 128       // stats accumulator slots (contention spread)

typedef unsigned short u16;
typedef short short8 __attribute__((ext_vector_type(8)));
typedef float f32x16 __attribute__((ext_vector_type(16)));
typedef unsigned int uintx4 __attribute__((ext_vector_type(4)));

// ---- workspace layout (float offsets) ----
#define F_KB   (BH*T*16/2)                   // bf16 K, 1M floats
#define F_VT   (BH*32768/2)                  // bf16 V2 32-row tiles, 2M floats
#define OFF_KB   0
#define OFF_VT   (OFF_KB + F_KB)             // V2 [bh][g=t/16][row 0..31][t%16]; row16=ones
#define OFF_ET   (OFF_VT + F_VT)             // f32 enhT [20ch][NROW]
#define OFF_WF   (OFF_ET + AC*NROW)
#define OFF_ACC  (OFF_WF + 5120)             // f32 accum[NSLOT][80]
#define OFF_ST   (OFF_ACC + NSLOT*80)        // f32 stats[40]

// fused-weight sub-offsets inside wf
#define WF_WQ 0
#define WF_BQ 1024
#define WF_WK 1088
#define WF_BK 2368
#define WF_WV 2432
#define WF_BV 3712
#define WF_WO 3776
#define WF_BO 5056
#define WF_TOTAL 5076

// 0.25 (1/sqrt(HD)) x log2(e): scores come out of MFMA in log2 domain
#define QSCALE 0.36067375670234045f

__device__ __forceinline__ u16 bf16b(float a) {
    __hip_bfloat16 t = __float2bfloat16(a);
    u16 u; __builtin_memcpy(&u, &t, 2); return u;
}
__device__ __forceinline__ unsigned packbf(float a, float b) {
    return (unsigned)bf16b(a) | ((unsigned)bf16b(b) << 16);
}

// ---------------- K0: fuse weights (+ zero stats accumulator slots) ----------------
__global__ __launch_bounds__(256) void k_fuse(
    const float* __restrict__ Wq, const float* __restrict__ bq,
    const float* __restrict__ Wkv, const float* __restrict__ bkv,
    const float* __restrict__ in_w, const float* __restrict__ in_b,
    const float* __restrict__ out_w, const float* __restrict__ out_b,
    const float* __restrict__ proj_w, const float* __restrict__ proj_b,
    float* __restrict__ wf, float* __restrict__ accum) {
    int idx = blockIdx.x * 256 + threadIdx.x;
    if (idx < NSLOT*40) {                    // zero accum[NSLOT][80], 2 per thread
        accum[idx] = 0.f;
        accum[idx + NSLOT*40] = 0.f;
    }
    if (idx >= WF_TOTAL) return;
    if (idx < WF_BQ) {                       // WqF[i][j] (scale 0.25*log2e folded)
        int i = idx >> 4, j = idx & 15;
        float s = 0.f;
        for (int m = 0; m < H; ++m) s += in_w[i*H + m] * Wq[m*SE + j];
        wf[idx] = QSCALE * s;
    } else if (idx < WF_WK) {                // bqF
        int i = idx - WF_BQ;
        float s = in_b[i];
        for (int m = 0; m < H; ++m) s += in_w[i*H + m] * bq[m];
        wf[idx] = QSCALE * s;
    } else if (idx < WF_BK) {                // WkF[i][j]
        int r = idx - WF_WK; int i = r / AC, j = r % AC;
        float s = 0.f;
        for (int m = 0; m < H; ++m) s += in_w[(H+i)*H + m] * Wkv[m*AC + j];
        wf[idx] = s;
    } else if (idx < WF_WV) {                // bkF
        int i = idx - WF_BK;
        float s = in_b[H + i];
        for (int m = 0; m < H; ++m) s += in_w[(H+i)*H + m] * bkv[m];
        wf[idx] = s;
    } else if (idx < WF_BV) {                // WvF[i][j]
        int r = idx - WF_WV; int i = r / AC, j = r % AC;
        float s = 0.f;
        for (int m = 0; m < H; ++m) s += in_w[(2*H+i)*H + m] * Wkv[(H+m)*AC + j];
        wf[idx] = s;
    } else if (idx < WF_WO) {                // bvF
        int i = idx - WF_BV;
        float s = in_b[2*H + i];
        for (int m = 0; m < H; ++m) s += in_w[(2*H+i)*H + m] * bkv[H + m];
        wf[idx] = s;
    } else if (idx < WF_BO) {                // WoF[c][d]
        int r = idx - WF_WO; int c = r >> 6, d = r & 63;
        float s = 0.f;
        for (int m = 0; m < H; ++m) s += proj_w[c*H + m] * out_w[m*H + d];
        wf[idx] = s;
    } else {                                 // boF
        int c = idx - WF_BO;
        float s = proj_b[c];
        for (int m = 0; m < H; ++m) s += proj_w[c*H + m] * out_b[m];
        wf[idx] = s;
    }
}

// ---------------- K1: fused KV projection ----------------
// block = 128 threads = 16 rows x 8 sections; sections 0-3 = K heads, 4-7 = V heads.
// V tile transposed through padded LDS -> coalesced dwordx4 global writes.
// V2 tile = 32 rows x 16 keys; rows 0-15 = V^T, row 16 = ones (MFMA denominator row).
__global__ __launch_bounds__(128) void k_qkv(
    const float* __restrict__ acst, const float* __restrict__ wf,
    u16* __restrict__ Kb, u16* __restrict__ Vtb) {
    __shared__ __align__(16) unsigned vls32[16*33];   // V tile [d][h*8+rp], stride-33 dwords
    const int tid = threadIdx.x;
    const int sec = tid >> 4, r = tid & 15;
    const int row = blockIdx.x * 16 + r;
    const int b = row >> 10, t = row & 1023;
    const int type = sec >> 2, h = sec & 3;           // type 0=K, 1=V
    float o[16];
    {
        float a[AC];
        const float4* ap = (const float4*)(acst + (size_t)row * AC);
        #pragma unroll
        for (int i = 0; i < 5; ++i) {
            float4 v = ap[i];
            a[4*i] = v.x; a[4*i+1] = v.y; a[4*i+2] = v.z; a[4*i+3] = v.w;
        }
        const float* wb = wf + (type == 0 ? WF_WK : WF_WV) + h*16*AC;
        const float* bb = wf + (type == 0 ? WF_BK : WF_BV) + h*16;
        #pragma unroll
        for (int ii = 0; ii < 16; ++ii) {
            float acc = bb[ii];
            #pragma unroll
            for (int j = 0; j < 5; ++j) {
                float4 w4 = *(const float4*)(wb + ii*AC + 4*j);
                acc += a[4*j]*w4.x + a[4*j+1]*w4.y + a[4*j+2]*w4.z + a[4*j+3]*w4.w;
            }
            o[ii] = acc;
        }
    }
    if (type == 0) {
        unsigned* dst = (unsigned*)(Kb + (((size_t)(b*NH + h))*T + t)*16);
        #pragma unroll
        for (int i = 0; i < 8; ++i) dst[i] = packbf(o[2*i], o[2*i+1]);
    } else {
        u16* v16 = (u16*)vls32;               // u16 idx = d*66 + h*16 + r (2-way banks = free)
        #pragma unroll
        for (int d = 0; d < HD; ++d) v16[d*66 + h*16 + r] = bf16b(o[d]);
    }
    __syncthreads();
    if (type == 1) {
        // copy V tile to global: thread (h2,li) owns dst row d=li of head h2
        const int l = tid - 64, h2 = l >> 4, li = l & 15;
        const int bb_ = blockIdx.x >> 6, g = blockIdx.x & 63;
        const size_t tile = (size_t)((bb_*NH + h2)*64 + g);
        unsigned tmp[8];
        #pragma unroll
        for (int k = 0; k < 8; ++k) tmp[k] = vls32[li*33 + h2*8 + k];
        unsigned* dst = (unsigned*)(Vtb + tile*512) + li*8;
        *(uintx4*)dst       = (uintx4){tmp[0], tmp[1], tmp[2], tmp[3]};
        *(uintx4*)(dst + 4) = (uintx4){tmp[4], tmp[5], tmp[6], tmp[7]};
        if (li == 0) {                        // denominator row 16 = bf16 ones
            unsigned* od = (unsigned*)(Vtb + tile*512 + 256);
            const unsigned one2 = 0x3F803F80u;
            *(uintx4*)od       = (uintx4){one2, one2, one2, one2};
            *(uintx4*)(od + 4) = (uintx4){one2, one2, one2, one2};
        }
    }
}

// ---------------- K2: Q-proj + MFMA flash attention + output proj + residual + stats ----------------
// block = 4 waves = 4 heads x 32 q-rows x full 1024 keys; grid = 1024
// b = blk&31: all 32 q-tiles of batch b land on XCD b%8 (K/V of 4 heads L2-local).
// Scores in log2 domain (QSCALE folds log2e); exponential = raw v_exp_f32 via
// __builtin_amdgcn_exp2f (R11 lesson: exp2f() is the PRECISE libm path, ~6 VALU ops).
// NOTE (R10 lesson): NO per-block __threadfence — device-scope fence = L2 flush storm.
#define CSTR 66
__global__ __launch_bounds__(256, 4) void k_attn(
    const float* __restrict__ sem,
    const u16* __restrict__ Kb, const u16* __restrict__ Vtb,
    const float* __restrict__ acst, const float* __restrict__ wf,
    const float* __restrict__ rlogit,
    float* __restrict__ enhT, float* __restrict__ accum) {
    __shared__ __align__(16) float ctxs[32*CSTR];   // 8.25 KB, stride-66 (2-way banks = free)
    __shared__ __align__(16) float wsm[AC*H + AC];  // 5.2 KB out-proj weights
    __shared__ __align__(16) float wqs[16*H + H];   // 4.25 KB WqF + bqF
    const int tid  = threadIdx.x;
    const int lane = tid & 63;
    const int wv   = tid >> 6;                      // wave = head
    for (int i = tid; i < AC*H + AC; i += 256) wsm[i] = wf[WF_WO + i];
    for (int i = tid; i < 16*H + H; i += 256) wqs[i] = wf[WF_WQ + i];
    const int blk  = blockIdx.x;
    const int b    = blk & 31;
    const int qblk = blk >> 5;
    const int l31 = lane & 31, hi2 = lane >> 5;
    const int bh = b*NH + wv;
    const int q0 = qblk*32;
    __syncthreads();

    // ---- Q fragment computed in-place (QSCALE folded in wqs) ----
    short8 qf;
    {
        float s[SE];
        const float4* sp = (const float4*)(sem + ((size_t)b*T + q0 + l31) * SE);
        #pragma unroll
        for (int i = 0; i < 4; ++i) {
            float4 v = sp[i];
            s[4*i] = v.x; s[4*i+1] = v.y; s[4*i+2] = v.z; s[4*i+3] = v.w;
        }
        #pragma unroll
        for (int jj = 0; jj < 8; ++jj) {
            const int ii = wv*16 + hi2*8 + jj;
            float acc0 = wqs[1024 + ii];
            #pragma unroll
            for (int j = 0; j < 4; ++j) {
                float4 w4 = *(const float4*)(wqs + ii*SE + 4*j);
                acc0 += s[4*j]*w4.x + s[4*j+1]*w4.y + s[4*j+2]*w4.z + s[4*j+3]*w4.w;
            }
            qf[jj] = (short)bf16b(acc0);
        }
    }

    // A-fragment K: K[key][d], key = lane&31 (+32/chunk), d = 8*hi2 + j
    const u16* kp = Kb + ((size_t)bh*T + l31)*16 + 8*hi2;
    // A-fragment V2: row = lane&31 (0-15 = d, 16 = ones), k-half by hi2; 1024 u16/chunk
    const u16* vp = Vtb + (size_t)bh*32768 + l31*16 + 8*hi2;

    f32x16 acc = {0.f,0.f,0.f,0.f,0.f,0.f,0.f,0.f,0.f,0.f,0.f,0.f,0.f,0.f,0.f,0.f};
    const f32x16 z16 = {0.f,0.f,0.f,0.f,0.f,0.f,0.f,0.f,0.f,0.f,0.f,0.f,0.f,0.f,0.f,0.f};

    auto chunk = [&](short8 kf, short8 va, short8 vb) {
        // scores^T[key][q] in log2 domain: C col = q (lane-local)
        f32x16 sc = __builtin_amdgcn_mfma_f32_32x32x16_bf16(kf, qf, z16, 0, 0, 0);
        float p[16];
        #pragma unroll
        for (int r = 0; r < 16; ++r) p[r] = __builtin_amdgcn_exp2f(sc[r]);
        // pack P pairs with HW cvt (RNE)
        unsigned u0, u1, u2, u3, u4, u5, u6, u7;
        asm("v_cvt_pk_bf16_f32 %0, %1, %2" : "=v"(u0) : "v"(p[0]),  "v"(p[1]));
        asm("v_cvt_pk_bf16_f32 %0, %1, %2" : "=v"(u1) : "v"(p[2]),  "v"(p[3]));
        asm("v_cvt_pk_bf16_f32 %0, %1, %2" : "=v"(u2) : "v"(p[4]),  "v"(p[5]));
        asm("v_cvt_pk_bf16_f32 %0, %1, %2" : "=v"(u3) : "v"(p[6]),  "v"(p[7]));
        asm("v_cvt_pk_bf16_f32 %0, %1, %2" : "=v"(u4) : "v"(p[8]),  "v"(p[9]));
        asm("v_cvt_pk_bf16_f32 %0, %1, %2" : "=v"(u5) : "v"(p[10]), "v"(p[11]));
        asm("v_cvt_pk_bf16_f32 %0, %1, %2" : "=v"(u6) : "v"(p[12]), "v"(p[13]));
        asm("v_cvt_pk_bf16_f32 %0, %1, %2" : "=v"(u7) : "v"(p[14]), "v"(p[15]));
        // in-register transpose across lane halves (T12)
        asm("v_permlane32_swap_b32 %0, %1" : "+v"(u2), "+v"(u0));
        asm("v_permlane32_swap_b32 %0, %1" : "+v"(u3), "+v"(u1));
        asm("v_permlane32_swap_b32 %0, %1" : "+v"(u6), "+v"(u4));
        asm("v_permlane32_swap_b32 %0, %1" : "+v"(u7), "+v"(u5));
        uintx4 t1 = {u0, u1, u2, u3};
        uintx4 t2 = {u4, u5, u6, u7};
        short8 pf1 = __builtin_bit_cast(short8, t1);
        short8 pf2 = __builtin_bit_cast(short8, t2);
        acc = __builtin_amdgcn_mfma_f32_32x32x16_bf16(va, pf1, acc, 0, 0, 0);
        acc = __builtin_amdgcn_mfma_f32_32x32x16_bf16(vb, pf2, acc, 0, 0, 0);
    };

    // depth-2 software pipeline (static register rotation)
    short8 kfA = *(const short8*)kp;
    short8 vaA = *(const short8*)vp;
    short8 vbA = *(const short8*)(vp + 512);
    short8 kfB = *(const short8*)(kp + 512);
    short8 vaB = *(const short8*)(vp + 1024);
    short8 vbB = *(const short8*)(vp + 1536);
    for (int ch = 0; ch < NCHUNK; ch += 2) {
        const int n0 = (ch + 2 < NCHUNK) ? ch + 2 : ch;
        short8 kfN0 = *(const short8*)(kp + (size_t)n0*512);
        short8 vaN0 = *(const short8*)(vp + (size_t)n0*1024);
        short8 vbN0 = *(const short8*)(vp + (size_t)n0*1024 + 512);
        chunk(kfA, vaA, vbA);
        const int n1 = (ch + 3 < NCHUNK) ? ch + 3 : ch + 1;
        short8 kfN1 = *(const short8*)(kp + (size_t)n1*512);
        short8 vaN1 = *(const short8*)(vp + (size_t)n1*1024);
        short8 vbN1 = *(const short8*)(vp + (size_t)n1*1024 + 512);
        chunk(kfB, vaB, vbB);
        kfA = kfN0; vaA = vaN0; vbA = vbN0;
        kfB = kfN1; vaB = vaN1; vbB = vbN1;
    }

    // denominator: C-row 16 = ones-row dot P = sum over all keys of bf16(P)
    const float ls = __shfl(acc[8], l31);   // lane l31 has hi2=0 -> row 16
    const float inv = 1.f / ls;
    #pragma unroll
    for (int r = 0; r < 8; ++r) {           // regs 0-7 = d rows 0-15
        const int d = (r & 3) + 8*(r >> 2) + 4*hi2;
        ctxs[l31*CSTR + wv*16 + d] = acc[r] * inv;
    }
    __syncthreads();

    // ---- fused output proj + residual + slot-spread channel stats ----
    const int rq = tid & 31, g = tid >> 5;  // half-wave g owns channels {g+8j}
    const int row = b*T + q0 + rq;
    const float sg = 1.f / (1.f + __expf(-rlogit[0]));
    float* slot = accum + (size_t)(blk & (NSLOT-1)) * 80;
    const int nj = (g < 4) ? 3 : 2;         // wave-uniform (g paired per wave)
    for (int j = 0; j < nj; ++j) {
        const int ch = g + 8*j;
        float s = wsm[AC*H + ch];
        #pragma unroll
        for (int kc = 0; kc < 4; ++kc) {    // k-chunked dot, scalar LDS reads
            float c0 = ctxs[rq*CSTR + kc*16 +  0], c1 = ctxs[rq*CSTR + kc*16 +  1];
            float c2 = ctxs[rq*CSTR + kc*16 +  2], c3 = ctxs[rq*CSTR + kc*16 +  3];
            float c4 = ctxs[rq*CSTR + kc*16 +  4], c5 = ctxs[rq*CSTR + kc*16 +  5];
            float c6 = ctxs[rq*CSTR + kc*16 +  6], c7 = ctxs[rq*CSTR + kc*16 +  7];
            float c8 = ctxs[rq*CSTR + kc*16 +  8], c9 = ctxs[rq*CSTR + kc*16 +  9];
            float cA = ctxs[rq*CSTR + kc*16 + 10], cB = ctxs[rq*CSTR + kc*16 + 11];
            float cC = ctxs[rq*CSTR + kc*16 + 12], cD = ctxs[rq*CSTR + kc*16 + 13];
            float cE = ctxs[rq*CSTR + kc*16 + 14], cF = ctxs[rq*CSTR + kc*16 + 15];
            const float* w = wsm + ch*H + kc*16;
            s += c0*w[0] + c1*w[1] + c2*w[2] + c3*w[3]
               + c4*w[4] + c5*w[5] + c6*w[6] + c7*w[7]
               + c8*w[8] + c9*w[9] + cA*w[10] + cB*w[11]
               + cC*w[12] + cD*w[13] + cE*w[14] + cF*w[15];
        }
        const float a = acst[(size_t)row*AC + ch];
        const float e = a + sg * s;
        enhT[(size_t)ch * NROW + row] = e;
        float sa = a, qa = a*a, se = e, qe = e*e;
        #pragma unroll
        for (int m = 1; m <= 16; m <<= 1) { // reduce within 32-lane half-wave
            sa += __shfl_xor(sa, m); qa += __shfl_xor(qa, m);
            se += __shfl_xor(se, m); qe += __shfl_xor(qe, m);
        }
        if (rq == 0) {
            atomicAdd(&slot[ch*4+0], sa);
            atomicAdd(&slot[ch*4+1], qa);
            atomicAdd(&slot[ch*4+2], se);
            atomicAdd(&slot[ch*4+3], qe);
        }
    }
}

// ---------------- K3: reduce accumulator slots -> per-channel (mu, corr) ----------------
// one block, 640 threads = 80 counters x 8 slot-parts (16 slots each)
__global__ __launch_bounds__(640) void k_stats2(
    const float* __restrict__ accum, float* __restrict__ stats) {
    __shared__ float red[80*8];
    __shared__ float acs[80];
    const int tx = threadIdx.x;
    const int c = tx >> 3, p = tx & 7;
    float s0 = 0.f, s1 = 0.f, s2 = 0.f, s3 = 0.f;
    #pragma unroll
    for (int i = 0; i < 4; ++i) {
        int sl = p + (4*i)*8;
        s0 += accum[(size_t)sl*80 + c];
        s1 += accum[(size_t)(sl+8)*80 + c];
        s2 += accum[(size_t)(sl+16)*80 + c];
        s3 += accum[(size_t)(sl+24)*80 + c];
    }
    red[c*8 + p] = (s0 + s1) + (s2 + s3);
    __syncthreads();
    if (tx < 80) {
        float t = 0.f;
        #pragma unroll
        for (int i = 0; i < 8; ++i) t += red[tx*8 + i];
        acs[tx] = t;
    }
    __syncthreads();
    if (tx < AC) {
        const float Nf = (float)NROW;
        float sa = acs[tx*4+0], qa = acs[tx*4+1];
        float se = acs[tx*4+2], qe = acs[tx*4+3];
        float mu  = sa / Nf;
        float va  = (qa - sa*sa/Nf) / (Nf - 1.f);
        float sda = sqrtf(fmaxf(va, 0.f));
        float osd = sda + 1e-8f;
        float ve  = (qe - se*se/Nf) / (Nf - 1.f);
        float sde = sqrtf(fmaxf(ve, 0.f));
        float ratio = (sde / osd) / (sda / osd + 1e-8f);
        float corr  = (ratio < 0.4f) ? (0.4f / ratio) : 1.f;
        stats[tx*2]   = mu;
        stats[tx*2+1] = corr;
    }
}

// ---------------- K4: std-correction + LayerNorm (reads precomputed stats) ----------------
__global__ __launch_bounds__(128) void k_final(
    const float* __restrict__ enhT, const float* __restrict__ stats,
    const float* __restrict__ gamma, const float* __restrict__ beta,
    float* __restrict__ out) {
    __shared__ float acs[40];
    const int tx = threadIdx.x;
    if (tx < 40) acs[tx] = stats[tx];
    __syncthreads();
    int row = blockIdx.x * 128 + tx;
    float ef[AC];
    #pragma unroll
    for (int c = 0; c < AC; ++c) {
        float mu = acs[c*2], corr = acs[c*2+1];
        float e = enhT[(size_t)c * NROW + row];
        ef[c] = (e - mu) * corr + mu;
    }
    float m = 0.f;
    #pragma unroll
    for (int c = 0; c < AC; ++c) m += ef[c];
    m *= (1.f / AC);
    float v = 0.f;
    #pragma unroll
    for (int c = 0; c < AC; ++c) { float d = ef[c] - m; v += d*d; }
    v *= (1.f / AC);
    float inv = rsqrtf(v + 1e-5f);
    float o[AC];
    #pragma unroll
    for (int c = 0; c < AC; ++c) o[c] = (ef[c] - m) * inv * gamma[c] + beta[c];
    float4* op = (float4*)(out + (size_t)row * AC);
    #pragma unroll
    for (int i = 0; i < 5; ++i)
        op[i] = make_float4(o[4*i], o[4*i+1], o[4*i+2], o[4*i+3]);
}

extern "C" void kernel_launch(void* const* d_in, const int* in_sizes, int n_in,
                              void* d_out, int out_size, void* d_ws, size_t ws_size,
                              hipStream_t stream) {
    (void)in_sizes; (void)n_in; (void)out_size; (void)ws_size;
    const float* acoustic = (const float*)d_in[0];
    const float* semantic = (const float*)d_in[1];
    const float* Wq     = (const float*)d_in[2];
    const float* bq     = (const float*)d_in[3];
    const float* Wkv    = (const float*)d_in[4];
    const float* bkv    = (const float*)d_in[5];
    const float* in_w   = (const float*)d_in[6];
    const float* in_b   = (const float*)d_in[7];
    const float* out_w  = (const float*)d_in[8];
    const float* out_b  = (const float*)d_in[9];
    const float* proj_w = (const float*)d_in[10];
    const float* proj_b = (const float*)d_in[11];
    const float* rlogit = (const float*)d_in[12];
    const float* gamma  = (const float*)d_in[13];
    const float* beta   = (const float*)d_in[14];
    float* ws = (float*)d_ws;
    u16* Kb  = (u16*)(ws + OFF_KB);
    u16* Vtb = (u16*)(ws + OFF_VT);
    float* enhT  = ws + OFF_ET;
    float* wf    = ws + OFF_WF;
    float* accum = ws + OFF_ACC;
    float* stats = ws + OFF_ST;
    float* out = (float*)d_out;

    k_fuse<<<(WF_TOTAL + 255)/256, 256, 0, stream>>>(Wq, bq, Wkv, bkv, in_w, in_b,
                                                     out_w, out_b, proj_w, proj_b, wf, accum);
    k_qkv<<<NROW/16, 128, 0, stream>>>(acoustic, wf, Kb, Vtb);
    k_attn<<<1024, 256, 0, stream>>>(semantic, Kb, Vtb, acoustic, wf, rlogit, enhT, accum);
    k_stats2<<<1, 640, 0, stream>>>(accum, stats);
    k_final<<<NROW/128, 128, 0, stream>>>(enhT, stats, gamma, beta, out);
}